// Round 1
// baseline (255.920 us; speedup 1.0000x reference)
//
#include <hip/hip_runtime.h>

#define NV 12
#define CIN 384
#define COUT 32
#define HW 4096        // 64*64 feature pixels
#define NVOX 262144    // 64^3 voxels

// Kernel 1: channel reduction 384 -> 32.
// feats_ws[bv][pix][o] = sum_c vit[bv][c][pix] * w[o][c] + bias[o]
// w/bias accesses are wave-uniform -> compiler emits s_load, FMA with SGPR operand.
__global__ __launch_bounds__(256) void mv_reduce_kernel(
    const float* __restrict__ vit, const float* __restrict__ w,
    const float* __restrict__ bias, float* __restrict__ feats)
{
    const int bv  = blockIdx.x;                       // 0..47  (b*12+v)
    const int pix = blockIdx.y * 256 + threadIdx.x;   // 0..4095
    const float* src = vit + (size_t)bv * CIN * HW + pix;

    float acc[COUT];
#pragma unroll
    for (int o = 0; o < COUT; ++o) acc[o] = bias[o];

#pragma unroll 4
    for (int c = 0; c < CIN; ++c) {
        const float x = src[(size_t)c * HW];
#pragma unroll
        for (int o = 0; o < COUT; ++o)
            acc[o] = fmaf(x, w[o * CIN + c], acc[o]);
    }

    float* dst = feats + ((size_t)bv * HW + pix) * COUT;
#pragma unroll
    for (int o = 0; o < COUT; o += 4) {
        *reinterpret_cast<float4*>(dst + o) =
            make_float4(acc[o], acc[o + 1], acc[o + 2], acc[o + 3]);
    }
}

// Kernel 2: backproject voxels into each view, gather 32-ch features, average.
// One thread per (b, voxel). Projection math in fp64 to make rounding
// decisions effectively exact (round-half-even via rint, matching jnp.round).
__global__ __launch_bounds__(256) void mv_fuse_kernel(
    const float* __restrict__ feats, const float* __restrict__ proj,
    float* __restrict__ out)
{
    __shared__ double P[NV][12];

    const int tid = threadIdx.x;
    const unsigned gid = blockIdx.x * 256u + tid;
    const int b = gid >> 18;            // 262144 voxels per batch
    const int n = gid & (NVOX - 1);

    if (tid < NV * 12) {
        const int v = tid / 12, e = tid - v * 12;
        const int r = e >> 2;                       // row 0..2
        const float s = (r < 2) ? 0.25f : 1.0f;     // projection[:, :, :2, :] / STRIDE
        P[v][e] = (double)(proj[((b * NV + v) * 3 + r) * 4 + (e & 3)] * s);
    }
    __syncthreads();

    const int k = n & 63, j = (n >> 6) & 63, i = n >> 12;
    const double wx = (double)i * 0.04 - 1.28;
    const double wy = (double)j * 0.04 - 1.28;
    const double wz = (double)k * 0.04 - 1.28;

    float acc[COUT];
#pragma unroll
    for (int o = 0; o < COUT; ++o) acc[o] = 0.0f;
    int cnt = 0;

    const float* fb = feats + (size_t)b * NV * HW * COUT;

    for (int v = 0; v < NV; ++v) {
        const double* p = P[v];
        const double cz = p[8] * wx + p[9] * wy + p[10] * wz + p[11];
        if (!(cz > 0.0)) continue;
        const double cx = p[0] * wx + p[1] * wy + p[2] * wz + p[3];
        const double cy = p[4] * wx + p[5] * wy + p[6] * wz + p[7];
        const double u = rint(cx / cz);   // round-half-even == jnp.round
        const double t = rint(cy / cz);
        if (u < 0.0 || u > 63.0 || t < 0.0 || t > 63.0) continue;
        const int px = (int)u, py = (int)t;

        const float4* s4 = reinterpret_cast<const float4*>(
            fb + ((size_t)(v * HW + py * 64 + px)) * COUT);
        ++cnt;
#pragma unroll
        for (int q = 0; q < 8; ++q) {
            const float4 f = s4[q];
            acc[q * 4 + 0] += f.x;
            acc[q * 4 + 1] += f.y;
            acc[q * 4 + 2] += f.z;
            acc[q * 4 + 3] += f.w;
        }
    }

    const float sc = (cnt > 0) ? (1.0f / (float)cnt) : 0.0f;
    float* ob = out + (size_t)b * COUT * NVOX + n;
#pragma unroll
    for (int o = 0; o < COUT; ++o)
        ob[(size_t)o * NVOX] = acc[o] * sc;
}

extern "C" void kernel_launch(void* const* d_in, const int* in_sizes, int n_in,
                              void* d_out, int out_size, void* d_ws, size_t ws_size,
                              hipStream_t stream) {
    const float* vit  = (const float*)d_in[0];  // (4,12,384,64,64)
    const float* w    = (const float*)d_in[1];  // (32,384)
    const float* bias = (const float*)d_in[2];  // (32,)
    const float* proj = (const float*)d_in[3];  // (4,12,3,4)
    float* out = (float*)d_out;                 // (4,32,64,64,64)
    float* feats = (float*)d_ws;                // 48*4096*32 floats = 25.2 MB

    dim3 g1(48, 16);
    mv_reduce_kernel<<<g1, 256, 0, stream>>>(vit, w, bias, feats);

    mv_fuse_kernel<<<4096, 256, 0, stream>>>(feats, proj, out);
}